// Round 11
// baseline (57.361 us; speedup 1.0000x reference)
//
#include <hip/hip_runtime.h>
#include <hip/hip_bf16.h>

#define L_CLS 2048
#define D_DIM 512
#define T_SZ  512
#define NT    511              // T-1 transitions per sequence
#define NOUT  (64 * NT)        // 32704
#define NCHUNK 16              // 128-col chunks
#define LDS_STRIDE 136         // 128 bf16 + pad -> 272 B rows
#define LOG2E 1.4426950408889634f
#define LN2   0.6931471805599453f
#define SHIFT 128.0f           // fixed exponent shift: sum 2^(x*log2e - SHIFT)

typedef __attribute__((ext_vector_type(8))) short bf16x8;
typedef __attribute__((ext_vector_type(4))) float f32x4;

static __device__ __forceinline__ short f2bf(float x) {
    return (short)__bfloat16_as_ushort(__float2bfloat16(x));
}

// MEASUREMENT ROUND: kernels identical to R10; each launched TWICE (both are
// idempotent pure functions of the inputs). dur_us - 31.6 = K1 + K2 (warm),
// separating in-kernel time from fixed per-replay/node overhead.

// ---------------------------------------------- fused conv + GEMM + exp-sums
__launch_bounds__(256)
__global__ void gemm_lse(const float* __restrict__ srcE,
                         const float* __restrict__ tgtE,
                         float* __restrict__ psum,
                         float* __restrict__ M, int useM) {
    __shared__ __hip_bfloat16 Blds[128 * LDS_STRIDE];   // 34816 B

    const int tid  = threadIdx.x;
    const int wave = tid >> 6;
    const int lane = tid & 63;
    const int lr   = lane & 15;
    const int hi   = lane >> 4;
    const int by   = blockIdx.x;
    const int bx   = blockIdx.y;
    const int C    = by * 128;
    const int R0   = bx * 64 + wave * 16;            // row-block 0
    const int R1   = (bx + 16) * 64 + wave * 16;     // row-block 1

    f32x4 acc[2][8];
#pragma unroll
    for (int rb = 0; rb < 2; ++rb)
#pragma unroll
        for (int ct = 0; ct < 8; ++ct) acc[rb][ct] = (f32x4){0.f, 0.f, 0.f, 0.f};

#pragma unroll 1
    for (int s = 0; s < 4; ++s) {    // K-slices of 128
#pragma unroll
        for (int i = 0; i < 8; ++i) {
            int p   = tid + 256 * i;         // 0..2047
            int row = p >> 4;                // 0..127
            int grp = p & 15;                // 8-elem group 0..15
            const f32x4* g = reinterpret_cast<const f32x4*>(
                tgtE + (C + row) * D_DIM + s * 128 + grp * 8);
            f32x4 x0 = g[0], x1 = g[1];
            bf16x8 v;
#pragma unroll
            for (int e = 0; e < 4; ++e) { v[e] = f2bf(x0[e]); v[e + 4] = f2bf(x1[e]); }
            *reinterpret_cast<bf16x8*>(&Blds[row * LDS_STRIDE + grp * 8]) = v;
        }
        __syncthreads();

        bf16x8 a[2][4];
#pragma unroll
        for (int rb = 0; rb < 2; ++rb) {
            const int R = rb ? R1 : R0;
            const float* arow = srcE + (R + lr) * D_DIM + s * 128 + hi * 8;
#pragma unroll
            for (int ks = 0; ks < 4; ++ks) {
                const f32x4* g = reinterpret_cast<const f32x4*>(arow + ks * 32);
                f32x4 x0 = g[0], x1 = g[1];
                bf16x8 v;
#pragma unroll
                for (int e = 0; e < 4; ++e) { v[e] = f2bf(x0[e]); v[e + 4] = f2bf(x1[e]); }
                a[rb][ks] = v;
            }
        }

#pragma unroll
        for (int ks = 0; ks < 4; ++ks) {
            const int off = ks * 32 + hi * 8;
#pragma unroll
            for (int ct = 0; ct < 8; ++ct) {
                bf16x8 b = *reinterpret_cast<const bf16x8*>(
                    &Blds[(ct * 16 + lr) * LDS_STRIDE + off]);
                acc[0][ct] = __builtin_amdgcn_mfma_f32_16x16x32_bf16(a[0][ks], b, acc[0][ct], 0, 0, 0);
                acc[1][ct] = __builtin_amdgcn_mfma_f32_16x16x32_bf16(a[1][ks], b, acc[1][ct], 0, 0, 0);
            }
        }
        __syncthreads();
    }

#pragma unroll
    for (int rb = 0; rb < 2; ++rb) {
        const int R = rb ? R1 : R0;
        if (useM) {
#pragma unroll
            for (int i = 0; i < 4; ++i) {
                size_t rg = (size_t)(R + hi * 4 + i) * L_CLS + C + lr;
#pragma unroll
                for (int ct = 0; ct < 8; ++ct)
                    M[rg + ct * 16] = acc[rb][ct][i];
            }
        }
        float p[4];
#pragma unroll
        for (int i = 0; i < 4; ++i) {
            p[i] = 0.f;
#pragma unroll
            for (int ct = 0; ct < 8; ++ct)
                p[i] += exp2f(acc[rb][ct][i] * LOG2E - SHIFT);
        }
#pragma unroll
        for (int off = 1; off < 16; off <<= 1)
#pragma unroll
            for (int i = 0; i < 4; ++i) p[i] += __shfl_xor(p[i], off);
        if (lr == 0) {
#pragma unroll
            for (int i = 0; i < 4; ++i)
                psum[(R + hi * 4 + i) * NCHUNK + by] = p[i];
        }
    }
}

// -------------------------------------------------------------- gather scores
__launch_bounds__(256)
__global__ void scores_gather(const int* __restrict__ labels,
                              const float* __restrict__ psum,
                              const float* __restrict__ M,
                              float* __restrict__ out) {
    int o = blockIdx.x * 256 + threadIdx.x;
    if (o >= NOUT) return;
    int b = o / NT;
    int t = o - b * NT;
    int src = labels[b * T_SZ + t];
    int tgt = labels[b * T_SZ + t + 1];

    const f32x4* pv = reinterpret_cast<const f32x4*>(psum + src * NCHUNK);
    f32x4 s0 = pv[0], s1 = pv[1], s2 = pv[2], s3 = pv[3];
    float S = (s0[0]+s0[1]+s0[2]+s0[3]) + (s1[0]+s1[1]+s1[2]+s1[3])
            + (s2[0]+s2[1]+s2[2]+s2[3]) + (s3[0]+s3[1]+s3[2]+s3[3]);
    float lse = (log2f(S) + SHIFT) * LN2;
    out[o] = M[(size_t)src * L_CLS + tgt] - lse;
}

// -------------------------------------- fallback: dot-product scores (no M ws)
__launch_bounds__(256)
__global__ void scores_dot(const int* __restrict__ labels,
                           const float* __restrict__ srcE,
                           const float* __restrict__ tgtE,
                           const float* __restrict__ psum,
                           float* __restrict__ out) {
    const int wid  = blockIdx.x * 4 + (threadIdx.x >> 6);
    const int lane = threadIdx.x & 63;
    const int b = wid / NT;
    const int t = wid - b * NT;
    const int src = labels[b * T_SZ + t];
    const int tgt = labels[b * T_SZ + t + 1];

    const f32x4* sp = reinterpret_cast<const f32x4*>(srcE + src * D_DIM + lane * 8);
    const f32x4* tp = reinterpret_cast<const f32x4*>(tgtE + tgt * D_DIM + lane * 8);
    f32x4 s0 = sp[0], s1 = sp[1];
    f32x4 t0 = tp[0], t1 = tp[1];
    float acc = 0.f;
#pragma unroll
    for (int j = 0; j < 4; ++j) acc += s0[j] * t0[j] + s1[j] * t1[j];
    float ps = (lane < NCHUNK) ? psum[src * NCHUNK + lane] : 0.f;
#pragma unroll
    for (int off = 32; off; off >>= 1) {
        acc += __shfl_xor(acc, off);
        ps  += __shfl_xor(ps, off);
    }
    if (lane == 0) out[wid] = acc - (log2f(ps) + SHIFT) * LN2;
}

// ------------------------------------------------------------------- launcher
extern "C" void kernel_launch(void* const* d_in, const int* in_sizes, int n_in,
                              void* d_out, int out_size, void* d_ws, size_t ws_size,
                              hipStream_t stream) {
    const int*   labels = (const int*)d_in[0];
    const float* srcE   = (const float*)d_in[1];
    const float* tgtE   = (const float*)d_in[2];
    float*       out    = (float*)d_out;

    float* psum = (float*)d_ws;                        // 128 KB
    float* M    = psum + L_CLS * NCHUNK;               // 16 MB

    size_t need = ((size_t)L_CLS * NCHUNK + (size_t)L_CLS * L_CLS) * sizeof(float);
    int useM = (ws_size >= need) ? 1 : 0;

    // Each kernel launched TWICE (idempotent): dur_us - 31.6 = K1 + K2 (warm).
    gemm_lse<<<dim3(NCHUNK, 16), 256, 0, stream>>>(srcE, tgtE, psum, M, useM);
    gemm_lse<<<dim3(NCHUNK, 16), 256, 0, stream>>>(srcE, tgtE, psum, M, useM);
    if (useM) {
        scores_gather<<<(NOUT + 255) / 256, 256, 0, stream>>>(labels, psum, M, out);
        scores_gather<<<(NOUT + 255) / 256, 256, 0, stream>>>(labels, psum, M, out);
    } else {
        scores_dot<<<NOUT / 4, 256, 0, stream>>>(labels, srcE, tgtE, psum, out);
        scores_dot<<<NOUT / 4, 256, 0, stream>>>(labels, srcE, tgtE, psum, out);
    }
}

// Round 12
// 27.603 us; speedup vs baseline: 2.0781x; 2.0781x over previous
//
#include <hip/hip_runtime.h>
#include <hip/hip_bf16.h>

#define L_CLS 2048
#define D_DIM 512
#define T_SZ  512
#define NT    511              // T-1 transitions per sequence
#define NOUT  (64 * NT)        // 32704
#define NCHUNK 16              // 128-col chunks
#define LDS_STRIDE 136         // 128 bf16 + pad -> 272 B rows
#define LOG2E 1.4426950408889634f
#define LN2   0.6931471805599453f
#define SHIFT 128.0f           // fixed exponent shift: sum 2^(x*log2e - SHIFT)

typedef __attribute__((ext_vector_type(8))) short bf16x8;
typedef __attribute__((ext_vector_type(4))) float f32x4;

static __device__ __forceinline__ short f2bf(float x) {
    return (short)__bfloat16_as_ushort(__float2bfloat16(x));
}

// ---------------------------------------------------------------- conv kernel
// f32 -> bf16 both tables (R2-validated). 2 MB/table output: fits per-XCD L2,
// halves GEMM read bytes, removes all cvt VALU work from the GEMM.
__global__ void conv_bf16(const float* __restrict__ srcE, const float* __restrict__ tgtE,
                          __hip_bfloat16* __restrict__ Sb, __hip_bfloat16* __restrict__ Tb) {
    int i = blockIdx.x * blockDim.x + threadIdx.x;   // groups of 8
    if (i >= (L_CLS * D_DIM) / 8) return;
    const f32x4* s4 = reinterpret_cast<const f32x4*>(srcE) + i * 2;
    const f32x4* t4 = reinterpret_cast<const f32x4*>(tgtE) + i * 2;
    f32x4 s0 = s4[0], s1 = s4[1];
    f32x4 t0 = t4[0], t1 = t4[1];
    bf16x8 so, to;
#pragma unroll
    for (int j = 0; j < 4; ++j) {
        so[j] = f2bf(s0[j]); so[j + 4] = f2bf(s1[j]);
        to[j] = f2bf(t0[j]); to[j + 4] = f2bf(t1[j]);
    }
    reinterpret_cast<bf16x8*>(Sb)[i] = so;
    reinterpret_cast<bf16x8*>(Tb)[i] = to;
}

// --------------------------------------------------- bf16 GEMM + exp-sums + M
// grid (16,16) x 512 thr (8 waves, 2/SIMD). WG tile 128x128; wave w owns rows
// [bx*128 + w*16, +16). Per K-slice of 128: B chunk (128 rows x 128 k bf16)
// staged via regs into padded LDS; next slice's B+A loads issued before the
// MFMA loop (fly under compute, T14 pattern). A-frags direct bf16x8 loads.
__launch_bounds__(512)
__global__ void gemm_lse_bf16(const __hip_bfloat16* __restrict__ Sb,
                              const __hip_bfloat16* __restrict__ Tb,
                              float* __restrict__ psum,
                              float* __restrict__ M) {
    __shared__ __hip_bfloat16 Blds[128 * LDS_STRIDE];   // 34816 B

    const int tid  = threadIdx.x;
    const int wave = tid >> 6;           // 0..7
    const int lane = tid & 63;
    const int lr   = lane & 15;
    const int hi   = lane >> 4;
    const int C    = blockIdx.x * 128;
    const int R    = blockIdx.y * 128 + wave * 16;

    f32x4 acc[8];
#pragma unroll
    for (int ct = 0; ct < 8; ++ct) acc[ct] = (f32x4){0.f, 0.f, 0.f, 0.f};

    bf16x8 stg[4], an[4];
    // prologue: slice 0 B-chunk + A-frags into regs
#pragma unroll
    for (int i = 0; i < 4; ++i) {
        int p = tid + 512 * i;           // 0..2047
        stg[i] = *reinterpret_cast<const bf16x8*>(
            &Tb[(C + (p >> 4)) * D_DIM + (p & 15) * 8]);
    }
#pragma unroll
    for (int ks = 0; ks < 4; ++ks)
        an[ks] = *reinterpret_cast<const bf16x8*>(
            &Sb[(R + lr) * D_DIM + ks * 32 + hi * 8]);

#pragma unroll 1
    for (int s = 0; s < 4; ++s) {
        // ds_write staged B chunk (padded stride)
#pragma unroll
        for (int i = 0; i < 4; ++i) {
            int p = tid + 512 * i;
            *reinterpret_cast<bf16x8*>(&Blds[(p >> 4) * LDS_STRIDE + (p & 15) * 8]) = stg[i];
        }
        bf16x8 a[4];
#pragma unroll
        for (int ks = 0; ks < 4; ++ks) a[ks] = an[ks];
        __syncthreads();

        if (s < 3) {   // prefetch next slice under the MFMAs
#pragma unroll
            for (int i = 0; i < 4; ++i) {
                int p = tid + 512 * i;
                stg[i] = *reinterpret_cast<const bf16x8*>(
                    &Tb[(C + (p >> 4)) * D_DIM + (s + 1) * 128 + (p & 15) * 8]);
            }
#pragma unroll
            for (int ks = 0; ks < 4; ++ks)
                an[ks] = *reinterpret_cast<const bf16x8*>(
                    &Sb[(R + lr) * D_DIM + (s + 1) * 128 + ks * 32 + hi * 8]);
        }

#pragma unroll
        for (int ks = 0; ks < 4; ++ks) {
            const int off = ks * 32 + hi * 8;
#pragma unroll
            for (int ct = 0; ct < 8; ++ct) {
                bf16x8 b = *reinterpret_cast<const bf16x8*>(
                    &Blds[(ct * 16 + lr) * LDS_STRIDE + off]);
                acc[ct] = __builtin_amdgcn_mfma_f32_16x16x32_bf16(a[ks], b, acc[ct], 0, 0, 0);
            }
        }
        __syncthreads();
    }

    // ---- epilogue: M writes + fixed-shift exp sums ----
    // D layout: col = C + ct*16 + lr, row = R + hi*4 + i.
#pragma unroll
    for (int i = 0; i < 4; ++i) {
        size_t rg = (size_t)(R + hi * 4 + i) * L_CLS + C + lr;
#pragma unroll
        for (int ct = 0; ct < 8; ++ct)
            M[rg + ct * 16] = acc[ct][i];
    }
    float p[4];
#pragma unroll
    for (int i = 0; i < 4; ++i) {
        p[i] = 0.f;
#pragma unroll
        for (int ct = 0; ct < 8; ++ct)
            p[i] += exp2f(acc[ct][i] * LOG2E - SHIFT);
    }
#pragma unroll
    for (int off = 1; off < 16; off <<= 1)
#pragma unroll
        for (int i = 0; i < 4; ++i) p[i] += __shfl_xor(p[i], off);
    if (lr == 0) {
#pragma unroll
        for (int i = 0; i < 4; ++i)
            psum[(R + hi * 4 + i) * NCHUNK + blockIdx.x] = p[i];
    }
}

// -------------------------------------------------------------- gather scores
__launch_bounds__(256)
__global__ void scores_gather(const int* __restrict__ labels,
                              const float* __restrict__ psum,
                              const float* __restrict__ M,
                              float* __restrict__ out) {
    int o = blockIdx.x * 256 + threadIdx.x;
    if (o >= NOUT) return;
    int b = o / NT;
    int t = o - b * NT;
    int src = labels[b * T_SZ + t];
    int tgt = labels[b * T_SZ + t + 1];

    const f32x4* pv = reinterpret_cast<const f32x4*>(psum + src * NCHUNK);
    f32x4 s0 = pv[0], s1 = pv[1], s2 = pv[2], s3 = pv[3];
    float S = (s0[0]+s0[1]+s0[2]+s0[3]) + (s1[0]+s1[1]+s1[2]+s1[3])
            + (s2[0]+s2[1]+s2[2]+s2[3]) + (s3[0]+s3[1]+s3[2]+s3[3]);
    float lse = (log2f(S) + SHIFT) * LN2;
    out[o] = M[(size_t)src * L_CLS + tgt] - lse;
}

// ===================== fallback path (R10, f32 tables) =======================
__launch_bounds__(256)
__global__ void gemm_lse_f32(const float* __restrict__ srcE,
                             const float* __restrict__ tgtE,
                             float* __restrict__ psum,
                             float* __restrict__ M, int useM) {
    __shared__ __hip_bfloat16 Blds[128 * LDS_STRIDE];
    const int tid  = threadIdx.x;
    const int wave = tid >> 6;
    const int lane = tid & 63;
    const int lr   = lane & 15;
    const int hi   = lane >> 4;
    const int C    = blockIdx.x * 128;
    const int R0   = blockIdx.y * 64 + wave * 16;
    const int R1   = (blockIdx.y + 16) * 64 + wave * 16;

    f32x4 acc[2][8];
#pragma unroll
    for (int rb = 0; rb < 2; ++rb)
#pragma unroll
        for (int ct = 0; ct < 8; ++ct) acc[rb][ct] = (f32x4){0.f, 0.f, 0.f, 0.f};

#pragma unroll 1
    for (int s = 0; s < 4; ++s) {
#pragma unroll
        for (int i = 0; i < 8; ++i) {
            int p = tid + 256 * i, row = p >> 4, grp = p & 15;
            const f32x4* g = reinterpret_cast<const f32x4*>(
                tgtE + (C + row) * D_DIM + s * 128 + grp * 8);
            f32x4 x0 = g[0], x1 = g[1];
            bf16x8 v;
#pragma unroll
            for (int e = 0; e < 4; ++e) { v[e] = f2bf(x0[e]); v[e + 4] = f2bf(x1[e]); }
            *reinterpret_cast<bf16x8*>(&Blds[row * LDS_STRIDE + grp * 8]) = v;
        }
        __syncthreads();
        bf16x8 a[2][4];
#pragma unroll
        for (int rb = 0; rb < 2; ++rb) {
            const float* arow = srcE + ((rb ? R1 : R0) + lr) * D_DIM + s * 128 + hi * 8;
#pragma unroll
            for (int ks = 0; ks < 4; ++ks) {
                const f32x4* g = reinterpret_cast<const f32x4*>(arow + ks * 32);
                f32x4 x0 = g[0], x1 = g[1];
                bf16x8 v;
#pragma unroll
                for (int e = 0; e < 4; ++e) { v[e] = f2bf(x0[e]); v[e + 4] = f2bf(x1[e]); }
                a[rb][ks] = v;
            }
        }
#pragma unroll
        for (int ks = 0; ks < 4; ++ks) {
            const int off = ks * 32 + hi * 8;
#pragma unroll
            for (int ct = 0; ct < 8; ++ct) {
                bf16x8 b = *reinterpret_cast<const bf16x8*>(&Blds[(ct * 16 + lr) * LDS_STRIDE + off]);
                acc[0][ct] = __builtin_amdgcn_mfma_f32_16x16x32_bf16(a[0][ks], b, acc[0][ct], 0, 0, 0);
                acc[1][ct] = __builtin_amdgcn_mfma_f32_16x16x32_bf16(a[1][ks], b, acc[1][ct], 0, 0, 0);
            }
        }
        __syncthreads();
    }
#pragma unroll
    for (int rb = 0; rb < 2; ++rb) {
        const int R = rb ? R1 : R0;
        if (useM) {
#pragma unroll
            for (int i = 0; i < 4; ++i) {
                size_t rg = (size_t)(R + hi * 4 + i) * L_CLS + C + lr;
#pragma unroll
                for (int ct = 0; ct < 8; ++ct) M[rg + ct * 16] = acc[rb][ct][i];
            }
        }
        float p[4];
#pragma unroll
        for (int i = 0; i < 4; ++i) {
            p[i] = 0.f;
#pragma unroll
            for (int ct = 0; ct < 8; ++ct) p[i] += exp2f(acc[rb][ct][i] * LOG2E - SHIFT);
        }
#pragma unroll
        for (int off = 1; off < 16; off <<= 1)
#pragma unroll
            for (int i = 0; i < 4; ++i) p[i] += __shfl_xor(p[i], off);
        if (lr == 0) {
#pragma unroll
            for (int i = 0; i < 4; ++i)
                psum[(R + hi * 4 + i) * NCHUNK + blockIdx.x] = p[i];
        }
    }
}

__launch_bounds__(256)
__global__ void scores_dot(const int* __restrict__ labels,
                           const float* __restrict__ srcE,
                           const float* __restrict__ tgtE,
                           const float* __restrict__ psum,
                           float* __restrict__ out) {
    const int wid  = blockIdx.x * 4 + (threadIdx.x >> 6);
    const int lane = threadIdx.x & 63;
    const int b = wid / NT;
    const int t = wid - b * NT;
    const int src = labels[b * T_SZ + t];
    const int tgt = labels[b * T_SZ + t + 1];
    const f32x4* sp = reinterpret_cast<const f32x4*>(srcE + src * D_DIM + lane * 8);
    const f32x4* tp = reinterpret_cast<const f32x4*>(tgtE + tgt * D_DIM + lane * 8);
    f32x4 s0 = sp[0], s1 = sp[1];
    f32x4 t0 = tp[0], t1 = tp[1];
    float acc = 0.f;
#pragma unroll
    for (int j = 0; j < 4; ++j) acc += s0[j] * t0[j] + s1[j] * t1[j];
    float ps = (lane < NCHUNK) ? psum[src * NCHUNK + lane] : 0.f;
#pragma unroll
    for (int off = 32; off; off >>= 1) {
        acc += __shfl_xor(acc, off);
        ps  += __shfl_xor(ps, off);
    }
    if (lane == 0) out[wid] = acc - (log2f(ps) + SHIFT) * LN2;
}

// ------------------------------------------------------------------- launcher
extern "C" void kernel_launch(void* const* d_in, const int* in_sizes, int n_in,
                              void* d_out, int out_size, void* d_ws, size_t ws_size,
                              hipStream_t stream) {
    const int*   labels = (const int*)d_in[0];
    const float* srcE   = (const float*)d_in[1];
    const float* tgtE   = (const float*)d_in[2];
    float*       out    = (float*)d_out;

    const size_t tbl = (size_t)L_CLS * D_DIM;
    const size_t needBF = 2 * tbl * sizeof(__hip_bfloat16)
                        + (size_t)L_CLS * NCHUNK * sizeof(float)
                        + (size_t)L_CLS * L_CLS * sizeof(float);   // ~20.3 MB

    if (ws_size >= needBF) {
        __hip_bfloat16* Sb = (__hip_bfloat16*)d_ws;          // 2 MB
        __hip_bfloat16* Tb = Sb + tbl;                       // 2 MB
        float* psum = (float*)((char*)d_ws + 2 * tbl * sizeof(__hip_bfloat16));
        float* M    = psum + (size_t)L_CLS * NCHUNK;         // 16 MB
        conv_bf16<<<(int)(tbl / 8 + 255) / 256, 256, 0, stream>>>(srcE, tgtE, Sb, Tb);
        gemm_lse_bf16<<<dim3(NCHUNK, 16), 512, 0, stream>>>(Sb, Tb, psum, M);
        scores_gather<<<(NOUT + 255) / 256, 256, 0, stream>>>(labels, psum, M, out);
    } else {
        float* psum = (float*)d_ws;
        float* M    = psum + (size_t)L_CLS * NCHUNK;
        size_t need = ((size_t)L_CLS * NCHUNK + (size_t)L_CLS * L_CLS) * sizeof(float);
        int useM = (ws_size >= need) ? 1 : 0;
        gemm_lse_f32<<<dim3(NCHUNK, 16), 256, 0, stream>>>(srcE, tgtE, psum, M, useM);
        if (useM)
            scores_gather<<<(NOUT + 255) / 256, 256, 0, stream>>>(labels, psum, M, out);
        else
            scores_dot<<<NOUT / 4, 256, 0, stream>>>(labels, srcE, tgtE, psum, out);
    }
}